// Round 1
// baseline (380.143 us; speedup 1.0000x reference)
//
#include <hip/hip_runtime.h>

#define BS 65536
#define DIM 64
#define SD 1024
#define TM 32
#define NTHREADS 512
#define TILE 128
#define NTILES 8
#define SROW 1028
#define LDS_BYTES 161024

// workspace layout (bytes)
#define WS_CB    0         // [1024][64] bf16  (row-major, for QK^T tiles)
#define WS_CBT   131072    // [8][64][128] bf16 (pre-tiled transposed, for PV tiles)
#define WS_C2    262144    // [1024] f32
#define WS_AVG   266240    // [1024] f32 accumulator
#define WS_LOSS  270336    // f32 accumulator

typedef __attribute__((ext_vector_type(8))) short bf16x8;
typedef __attribute__((ext_vector_type(4))) float f32x4;

__device__ __forceinline__ unsigned short f2bf(float f) {
  union { float f; unsigned int u; } v; v.f = f;
  unsigned int r = v.u + 0x7fffu + ((v.u >> 16) & 1u);
  return (unsigned short)(r >> 16);
}
__device__ __forceinline__ float bf2f(unsigned short h) {
  union { unsigned int u; float f; } v; v.u = ((unsigned int)h) << 16;
  return v.f;
}
__device__ __forceinline__ float wsum64(float v) {
  #pragma unroll
  for (int m = 1; m < 64; m <<= 1) v += __shfl_xor(v, m);
  return v;
}
__device__ __forceinline__ float wmax64(float v) {
  #pragma unroll
  for (int m = 1; m < 64; m <<= 1) v = fmaxf(v, __shfl_xor(v, m));
  return v;
}
__device__ __forceinline__ float gumb(float u) {
  // -log(-log(u + 1e-10) + 1e-10), matches reference EPS
  return -__logf(-__logf(u + 1e-10f) + 1e-10f);
}

// ---------------- prep: bf16 codebook copies (+transposed tiles), c2, zero accumulators ----------------
__global__ __launch_bounds__(256) void gvq_prep(const float* __restrict__ cb, char* __restrict__ ws) {
  unsigned short* cbb = (unsigned short*)(ws + WS_CB);
  unsigned short* cbt = (unsigned short*)(ws + WS_CBT);
  float* c2   = (float*)(ws + WS_C2);
  float* avg  = (float*)(ws + WS_AVG);
  float* lsum = (float*)(ws + WS_LOSS);
  int j = blockIdx.x * 256 + threadIdx.x;  // 0..1023
  if (j < SD) {
    float s = 0.f;
    int tt = j >> 7, jl = j & 127;
    #pragma unroll 8
    for (int d = 0; d < DIM; ++d) {
      float v = cb[j * DIM + d];
      s += v * v;
      unsigned short b = f2bf(v);
      cbb[j * DIM + d] = b;
      cbt[tt * (DIM * TILE) + d * TILE + jl] = b;
    }
    c2[j] = s;
    avg[j] = 0.f;
    if (j == 0) lsum[0] = 0.f;
  }
}

// ---------------- main fused kernel: 32 rows/block ----------------
__global__ __launch_bounds__(NTHREADS, 1) void gvq_main(
    const float* __restrict__ z, const float* __restrict__ pq,
    const float* __restrict__ u, char* __restrict__ ws,
    float* __restrict__ out)
{
  extern __shared__ char smem[];
  float* S              = (float*)smem;                     // [32][1028] f32 (scores, later bf16 encodings in-place)
  char* tilebuf         = smem + 131584;                    // 16 KB codebook tile (later zq[32][64] f32)
  unsigned short* zb    = (unsigned short*)(smem + 147968); // [32][72] bf16 (padded)
  float* c2s            = (float*)(smem + 152576);          // [1024]
  float* pavg           = (float*)(smem + 156672);          // [1024]
  float* z2s            = (float*)(smem + 160768);          // [32]
  float* zys            = (float*)(smem + 160896);          // [32]

  const int t    = threadIdx.x;
  const int lane = t & 63;
  const int wave = t >> 6;
  const int r0   = blockIdx.x * TM;
  const int l15  = lane & 15;
  const int lg   = lane >> 4;

  const unsigned short* cbb = (const unsigned short*)(ws + WS_CB);
  const char* cbtc          = ws + WS_CBT;
  const float* c2g          = (const float*)(ws + WS_C2);
  float* avgg               = (float*)(ws + WS_AVG);
  float* lsum               = (float*)(ws + WS_LOSS);

  const float weight = 0.5f / fmaxf(pq[0], 1e-10f);

  // ---- P0: stage z (f32->bf16), z2, c2, zero pavg ----
  {
    int row = t >> 4;
    int d0  = (t & 15) << 2;
    float4 zv = *(const float4*)(z + (size_t)(r0 + row) * DIM + d0);
    unsigned int p0 = (unsigned int)f2bf(zv.x) | ((unsigned int)f2bf(zv.y) << 16);
    unsigned int p1 = (unsigned int)f2bf(zv.z) | ((unsigned int)f2bf(zv.w) << 16);
    *(unsigned int*)((char*)zb + row * 144 + d0 * 2)     = p0;
    *(unsigned int*)((char*)zb + row * 144 + d0 * 2 + 4) = p1;
    float zs = zv.x*zv.x + zv.y*zv.y + zv.z*zv.z + zv.w*zv.w;
    zs += __shfl_xor(zs, 1); zs += __shfl_xor(zs, 2);
    zs += __shfl_xor(zs, 4); zs += __shfl_xor(zs, 8);
    if ((t & 15) == 0) z2s[row] = zs;
    c2s[t] = c2g[t]; c2s[t + 512] = c2g[t + 512];
    pavg[t] = 0.f;   pavg[t + 512] = 0.f;
  }
  uint4 st0 = *(const uint4*)((const char*)cbb + t * 32);
  uint4 st1 = *(const uint4*)((const char*)cbb + t * 32 + 16);
  __syncthreads();

  // ---- PA: scores S = -weight*(z2 + c2 - 2*z.c)  (MFMA 16x16x32 bf16) ----
  const int rb   = wave & 1;   // row block (16 rows)
  const int cgrp = wave >> 1;  // 32-col group within tile
  bf16x8 a0 = *(const bf16x8*)((const char*)zb + (rb * 16 + l15) * 144 + lg * 16);
  bf16x8 a1 = *(const bf16x8*)((const char*)zb + (rb * 16 + l15) * 144 + 64 + lg * 16);
  for (int tt = 0; tt < NTILES; ++tt) {
    *(uint4*)(tilebuf + t * 32)      = st0;
    *(uint4*)(tilebuf + t * 32 + 16) = st1;
    if (tt + 1 < NTILES) {
      st0 = *(const uint4*)((const char*)cbb + (tt + 1) * 16384 + t * 32);
      st1 = *(const uint4*)((const char*)cbb + (tt + 1) * 16384 + t * 32 + 16);
    }
    __syncthreads();
    #pragma unroll
    for (int cbk = 0; cbk < 2; ++cbk) {
      int jl = cgrp * 32 + cbk * 16;
      const char* bp = tilebuf + (jl + l15) * 128 + lg * 16;
      bf16x8 b0 = *(const bf16x8*)bp;
      bf16x8 b1 = *(const bf16x8*)(bp + 64);
      f32x4 acc = {0.f, 0.f, 0.f, 0.f};
      acc = __builtin_amdgcn_mfma_f32_16x16x32_bf16(a0, b0, acc, 0, 0, 0);
      acc = __builtin_amdgcn_mfma_f32_16x16x32_bf16(a1, b1, acc, 0, 0, 0);
      int jg = tt * TILE + jl + l15;
      float c2v = c2s[jg];
      int rl = rb * 16 + lg * 4;
      #pragma unroll
      for (int rr = 0; rr < 4; ++rr) {
        float logit = -weight * (z2s[rl + rr] + c2v - 2.f * acc[rr]);
        S[(rl + rr) * SROW + jg] = logit;
      }
    }
    __syncthreads();
  }

  // ---- PB+PC fused: per-row prob softmax stats + gumbel encodings (wave owns 4 rows) ----
  float kd_local = 0.f;
  float pav[16];
  #pragma unroll
  for (int i = 0; i < 16; ++i) pav[i] = 0.f;
  const int lr0 = wave * 4;
  for (int rr = 0; rr < 4; ++rr) {
    const int lr = lr0 + rr;
    float* Srow = S + lr * SROW;
    const float* urow = u + (size_t)(r0 + lr) * SD;
    float sval[16], uval[16];
    #pragma unroll
    for (int k = 0; k < 4; ++k) {
      float4 s4 = *(const float4*)(Srow + k * 256 + 4 * lane);
      float4 u4 = *(const float4*)(urow + k * 256 + 4 * lane);
      sval[4*k+0]=s4.x; sval[4*k+1]=s4.y; sval[4*k+2]=s4.z; sval[4*k+3]=s4.w;
      uval[4*k+0]=u4.x; uval[4*k+1]=u4.y; uval[4*k+2]=u4.z; uval[4*k+3]=u4.w;
    }
    // probabilities softmax: m, Z, E1 = sum e*(s-m); p*logp row sum = E1/Z - logZ
    float m = -1e30f;
    #pragma unroll
    for (int i = 0; i < 16; ++i) m = fmaxf(m, sval[i]);
    m = wmax64(m);
    float Zs = 0.f, E1 = 0.f, et[16];
    #pragma unroll
    for (int i = 0; i < 16; ++i) {
      float dsm = sval[i] - m;
      float e = __expf(dsm);
      Zs += e; E1 += e * dsm; et[i] = e;
    }
    Zs = wsum64(Zs); E1 = wsum64(E1);
    float invZ = 1.f / Zs;
    #pragma unroll
    for (int i = 0; i < 16; ++i) pav[i] += et[i] * invZ;
    kd_local += E1 * invZ - __logf(Zs);
    // gumbel path: y = s + g, unnormalized e=exp(y-my) stored bf16 in-place over S row
    float yv[16], my = -1e30f;
    #pragma unroll
    for (int i = 0; i < 16; ++i) {
      float y = sval[i] + gumb(uval[i]);
      yv[i] = y; my = fmaxf(my, y);
    }
    my = wmax64(my);
    float Zy = 0.f;
    #pragma unroll
    for (int k = 0; k < 4; ++k) {
      unsigned short e0 = f2bf(__expf(yv[4*k+0] - my));
      unsigned short e1 = f2bf(__expf(yv[4*k+1] - my));
      unsigned short e2 = f2bf(__expf(yv[4*k+2] - my));
      unsigned short e3 = f2bf(__expf(yv[4*k+3] - my));
      Zy += bf2f(e0) + bf2f(e1) + bf2f(e2) + bf2f(e3);
      uint2 pk;
      pk.x = (unsigned int)e0 | ((unsigned int)e1 << 16);
      pk.y = (unsigned int)e2 | ((unsigned int)e3 << 16);
      *(uint2*)((char*)Srow + k * 512 + 8 * lane) = pk;
    }
    Zy = wsum64(Zy);
    if (lane == 0) zys[lr] = Zy;
  }
  #pragma unroll
  for (int k = 0; k < 4; ++k) {
    #pragma unroll
    for (int c = 0; c < 4; ++c)
      atomicAdd(&pavg[k * 256 + 4 * lane + c], pav[4*k+c]);
  }
  __syncthreads();   // all encodings + pavg partials complete

  // ---- PD: z_q = E @ codebook  (K=1024, transposed bf16 tiles) ----
  st0 = *(const uint4*)(cbtc + t * 32);
  st1 = *(const uint4*)(cbtc + t * 32 + 16);
  f32x4 acc = {0.f, 0.f, 0.f, 0.f};
  const int db = wave >> 1;  // 16-col (dim) block
  for (int tt = 0; tt < NTILES; ++tt) {
    *(uint4*)(tilebuf + t * 32)      = st0;
    *(uint4*)(tilebuf + t * 32 + 16) = st1;
    if (tt + 1 < NTILES) {
      st0 = *(const uint4*)(cbtc + (tt + 1) * 16384 + t * 32);
      st1 = *(const uint4*)(cbtc + (tt + 1) * 16384 + t * 32 + 16);
    }
    __syncthreads();
    #pragma unroll
    for (int kb = 0; kb < 4; ++kb) {
      const char* ap = (const char*)S + (rb * 16 + l15) * 4112 + (tt * 128 + kb * 32 + lg * 8) * 2;
      bf16x8 a = *(const bf16x8*)ap;
      const char* bp = tilebuf + (db * 16 + l15) * 256 + (kb * 32 + lg * 8) * 2;
      bf16x8 b = *(const bf16x8*)bp;
      acc = __builtin_amdgcn_mfma_f32_16x16x32_bf16(a, b, acc, 0, 0, 0);
    }
    __syncthreads();
  }

  // ---- PE: normalize zq, write out, kld_continuous, flush scalars ----
  float* zq = (float*)tilebuf;  // reuse (8 KB)
  {
    int col = db * 16 + l15;
    int rl = rb * 16 + lg * 4;
    #pragma unroll
    for (int rr2 = 0; rr2 < 4; ++rr2) {
      float v = acc[rr2] / zys[rl + rr2];
      zq[(rl + rr2) * 64 + col] = v;
      out[(size_t)(r0 + rl + rr2) * DIM + col] = v;
    }
  }
  __syncthreads();
  float kc_local = 0.f;
  #pragma unroll
  for (int rr = 0; rr < 4; ++rr) {
    int lr = lr0 + rr;
    float zvv = z[(size_t)(r0 + lr) * DIM + lane];
    float dq = zvv - zq[lr * 64 + lane];
    kc_local += wsum64(dq * dq);
  }
  kc_local *= weight;
  if (lane == 0) atomicAdd(lsum, kd_local + kc_local);
  atomicAdd(&avgg[t],       pavg[t]);
  atomicAdd(&avgg[t + 512], pavg[t + 512]);
}

// ---------------- final: loss + perplexity ----------------
__global__ __launch_bounds__(256) void gvq_final(const char* __restrict__ ws, float* __restrict__ out) {
  const float* avgg = (const float*)(ws + WS_AVG);
  const float* lsum = (const float*)(ws + WS_LOSS);
  int t = threadIdx.x;
  float s = 0.f;
  for (int i = t; i < SD; i += 256) {
    float a = avgg[i] * (1.f / 65536.f);
    s += a * logf(a + 1e-7f);
  }
  s = wsum64(s);
  __shared__ float wsums[4];
  if ((t & 63) == 0) wsums[t >> 6] = s;
  __syncthreads();
  if (t == 0) {
    float tot = wsums[0] + wsums[1] + wsums[2] + wsums[3];
    out[(size_t)BS * DIM]     = lsum[0] * (1.f / 65536.f);
    out[(size_t)BS * DIM + 1] = expf(-tot);
  }
}

extern "C" void kernel_launch(void* const* d_in, const int* in_sizes, int n_in,
                              void* d_out, int out_size, void* d_ws, size_t ws_size,
                              hipStream_t stream) {
  (void)in_sizes; (void)n_in; (void)out_size; (void)ws_size;
  const float* z  = (const float*)d_in[0];
  const float* pq = (const float*)d_in[1];
  const float* cb = (const float*)d_in[2];
  const float* u  = (const float*)d_in[3];
  char* ws   = (char*)d_ws;
  float* out = (float*)d_out;
  hipFuncSetAttribute((const void*)gvq_main, hipFuncAttributeMaxDynamicSharedMemorySize, LDS_BYTES);
  gvq_prep<<<4, 256, 0, stream>>>(cb, ws);
  gvq_main<<<BS / TM, NTHREADS, LDS_BYTES, stream>>>(z, pq, u, ws, out);
  gvq_final<<<1, 256, 0, stream>>>(ws, out);
}

// Round 2
// 352.422 us; speedup vs baseline: 1.0787x; 1.0787x over previous
//
#include <hip/hip_runtime.h>

#define BS 65536
#define DIM 64
#define SD 1024
#define TM 32
#define NTHREADS 512
#define TILE 128
#define NTILES 8
#define SROW 1028
#define GSHIFT 23.1f

// LDS layout (bytes)
#define L_S      0         // [32][1028] f32 scores; PB overwrites first 2KB/row with ey bf16
#define L_TILE   131584    // 18432: PA tile 128x144B, PD tile 64x272B, PE zq 32x64 f32
#define L_ZB     150016    // [32][72] bf16 z staging (144B rows)
#define L_C2S    154624    // [1024] f32
#define L_PAVG   158720    // [1024] f32
#define L_Z2S    162816    // [32] f32
#define L_ZYS    162944    // [32] f32
#define L_RMX    163072    // [32] u32 (float-bits, atomicMin for max of negatives)
#define LDS_BYTES 163200

// workspace layout (bytes)
#define WS_CB    0         // [1024][64] bf16 codebook (row-major)
#define WS_CBT   131072    // [8][64][128] bf16 transposed tiles
#define WS_C2    262144    // [1024] f32
#define WS_AVG   266240    // [1024] f32 accumulator
#define WS_LOSS  270336    // f32 accumulator

typedef __attribute__((ext_vector_type(8))) short bf16x8;
typedef __attribute__((ext_vector_type(4))) float f32x4;

__device__ __forceinline__ unsigned short f2bf(float f) {
  union { float f; unsigned int u; } v; v.f = f;
  unsigned int r = v.u + 0x7fffu + ((v.u >> 16) & 1u);
  return (unsigned short)(r >> 16);
}
__device__ __forceinline__ float bf2f(unsigned short h) {
  union { unsigned int u; float f; } v; v.u = ((unsigned int)h) << 16;
  return v.f;
}
__device__ __forceinline__ float wsum64(float v) {
  #pragma unroll
  for (int m = 1; m < 64; m <<= 1) v += __shfl_xor(v, m);
  return v;
}
__device__ __forceinline__ float gumb(float u) {
  return -__logf(-__logf(u + 1e-10f) + 1e-10f);
}

// ---------------- prep ----------------
__global__ __launch_bounds__(256) void gvq_prep(const float* __restrict__ cb, char* __restrict__ ws) {
  unsigned short* cbb = (unsigned short*)(ws + WS_CB);
  unsigned short* cbt = (unsigned short*)(ws + WS_CBT);
  float* c2   = (float*)(ws + WS_C2);
  float* avg  = (float*)(ws + WS_AVG);
  float* lsum = (float*)(ws + WS_LOSS);
  int j = blockIdx.x * 256 + threadIdx.x;
  if (j < SD) {
    float s = 0.f;
    int tt = j >> 7, jl = j & 127;
    #pragma unroll 8
    for (int d = 0; d < DIM; ++d) {
      float v = cb[j * DIM + d];
      s += v * v;
      unsigned short b = f2bf(v);
      cbb[j * DIM + d] = b;
      cbt[tt * (DIM * TILE) + d * TILE + jl] = b;
    }
    c2[j] = s;
    avg[j] = 0.f;
    if (j == 0) lsum[0] = 0.f;
  }
}

// ---------------- main fused kernel ----------------
__global__ __launch_bounds__(NTHREADS, 2) void gvq_main(
    const float* __restrict__ z, const float* __restrict__ pq,
    const float* __restrict__ u, char* __restrict__ ws,
    float* __restrict__ out)
{
  extern __shared__ char smem[];
  float* S           = (float*)(smem + L_S);
  char*  tile        = smem + L_TILE;
  unsigned short* zb = (unsigned short*)(smem + L_ZB);
  float* c2s         = (float*)(smem + L_C2S);
  float* pavg        = (float*)(smem + L_PAVG);
  float* z2s         = (float*)(smem + L_Z2S);
  float* zys         = (float*)(smem + L_ZYS);
  unsigned int* rmxb = (unsigned int*)(smem + L_RMX);

  const int t    = threadIdx.x;
  const int lane = t & 63;
  const int wave = t >> 6;
  const int r0   = blockIdx.x * TM;
  const int l15  = lane & 15;
  const int lg   = lane >> 4;

  const unsigned short* cbb = (const unsigned short*)(ws + WS_CB);
  const char* cbtc          = ws + WS_CBT;
  const float* c2g          = (const float*)(ws + WS_C2);
  float* avgg               = (float*)(ws + WS_AVG);
  float* lsum               = (float*)(ws + WS_LOSS);

  const float weight = 0.5f / fmaxf(pq[0], 1e-10f);

  // ---- P0: stage z (bf16), z2, c2, init pavg/rowmax ----
  {
    int row = t >> 4;
    int d0  = (t & 15) << 2;
    float4 zv = *(const float4*)(z + (size_t)(r0 + row) * DIM + d0);
    unsigned int p0 = (unsigned int)f2bf(zv.x) | ((unsigned int)f2bf(zv.y) << 16);
    unsigned int p1 = (unsigned int)f2bf(zv.z) | ((unsigned int)f2bf(zv.w) << 16);
    *(unsigned int*)((char*)zb + row * 144 + d0 * 2)     = p0;
    *(unsigned int*)((char*)zb + row * 144 + d0 * 2 + 4) = p1;
    float zs = zv.x*zv.x + zv.y*zv.y + zv.z*zv.z + zv.w*zv.w;
    zs += __shfl_xor(zs, 1); zs += __shfl_xor(zs, 2);
    zs += __shfl_xor(zs, 4); zs += __shfl_xor(zs, 8);
    if ((t & 15) == 0) z2s[row] = zs;
    c2s[t] = c2g[t]; c2s[t + 512] = c2g[t + 512];
    pavg[t] = 0.f;   pavg[t + 512] = 0.f;
    if (t < TM) rmxb[t] = 0xFF800000u;  // -inf bits
  }
  uint4 st0 = *(const uint4*)((const char*)cbb + t * 32);
  uint4 st1 = *(const uint4*)((const char*)cbb + t * 32 + 16);
  __syncthreads();

  // ---- PA: S = -weight*(z2 + c2 - 2*z.c), track per-row max ----
  const int rb   = wave & 1;
  const int cgrp = wave >> 1;
  bf16x8 a0 = *(const bf16x8*)((const char*)zb + (rb * 16 + l15) * 144 + lg * 16);
  bf16x8 a1 = *(const bf16x8*)((const char*)zb + (rb * 16 + l15) * 144 + 64 + lg * 16);
  float rmax[4] = {-1e30f, -1e30f, -1e30f, -1e30f};
  for (int tt = 0; tt < NTILES; ++tt) {
    {
      char* dst = tile + (t >> 2) * 144 + (t & 3) * 32;
      *(uint4*)dst = st0; *(uint4*)(dst + 16) = st1;
    }
    if (tt + 1 < NTILES) {
      st0 = *(const uint4*)((const char*)cbb + (tt + 1) * 16384 + t * 32);
      st1 = *(const uint4*)((const char*)cbb + (tt + 1) * 16384 + t * 32 + 16);
    }
    __syncthreads();
    #pragma unroll
    for (int cbk = 0; cbk < 2; ++cbk) {
      int jl = cgrp * 32 + cbk * 16;
      const char* bp = tile + (jl + l15) * 144 + lg * 16;
      bf16x8 b0 = *(const bf16x8*)bp;
      bf16x8 b1 = *(const bf16x8*)(bp + 64);
      f32x4 acc = {0.f, 0.f, 0.f, 0.f};
      acc = __builtin_amdgcn_mfma_f32_16x16x32_bf16(a0, b0, acc, 0, 0, 0);
      acc = __builtin_amdgcn_mfma_f32_16x16x32_bf16(a1, b1, acc, 0, 0, 0);
      int jg = tt * TILE + jl + l15;
      float c2v = c2s[jg];
      int rl = rb * 16 + lg * 4;
      #pragma unroll
      for (int rr = 0; rr < 4; ++rr) {
        float logit = -weight * (z2s[rl + rr] + c2v - 2.f * acc[rr]);
        S[(rl + rr) * SROW + jg] = logit;
        rmax[rr] = fmaxf(rmax[rr], logit);
      }
    }
    __syncthreads();
  }
  // fold per-lane maxes -> per-row max (16-lane groups stay within xor<16)
  #pragma unroll
  for (int rr = 0; rr < 4; ++rr) {
    float v = rmax[rr];
    v = fmaxf(v, __shfl_xor(v, 1)); v = fmaxf(v, __shfl_xor(v, 2));
    v = fmaxf(v, __shfl_xor(v, 4)); v = fmaxf(v, __shfl_xor(v, 8));
    if (l15 == 0) atomicMin(&rmxb[rb * 16 + lg * 4 + rr], __float_as_uint(v));
  }
  __syncthreads();

  // ---- PB: single pass: e=exp(s-m) (regs), ey=exp(s+g-m-GSHIFT) -> bf16 in-place ----
  float kd_local = 0.f;
  float pav[16];
  #pragma unroll
  for (int i = 0; i < 16; ++i) pav[i] = 0.f;
  const int lr0 = wave * 4;
  const float* urow0 = u + (size_t)(r0 + lr0) * SD + 4 * lane;
  float4 ua0 = *(const float4*)(urow0);
  float4 ua1 = *(const float4*)(urow0 + 256);
  float4 ua2 = *(const float4*)(urow0 + 512);
  float4 ua3 = *(const float4*)(urow0 + 768);
  #pragma unroll
  for (int rr = 0; rr < 4; ++rr) {
    const int lr = lr0 + rr;
    float* Srow = S + lr * SROW;
    float4 uc0 = ua0, uc1 = ua1, uc2 = ua2, uc3 = ua3;
    if (rr < 3) {
      const float* un = urow0 + (size_t)(rr + 1) * SD;
      ua0 = *(const float4*)(un);
      ua1 = *(const float4*)(un + 256);
      ua2 = *(const float4*)(un + 512);
      ua3 = *(const float4*)(un + 768);
    }
    const float m   = __uint_as_float(rmxb[lr]);
    const float my0 = m + GSHIFT;
    float Zs = 0.f, E1 = 0.f, Zy = 0.f;
    float et[16];
#define PBCHUNK(K, UC) do { \
    float4 s4 = *(const float4*)(Srow + (K) * 256 + 4 * lane); \
    float d0s = s4.x - m, d1s = s4.y - m, d2s = s4.z - m, d3s = s4.w - m; \
    float e0 = __expf(d0s), e1 = __expf(d1s), e2 = __expf(d2s), e3 = __expf(d3s); \
    Zs += (e0 + e1) + (e2 + e3); \
    E1 += (e0 * d0s + e1 * d1s) + (e2 * d2s + e3 * d3s); \
    et[(K)*4+0] = e0; et[(K)*4+1] = e1; et[(K)*4+2] = e2; et[(K)*4+3] = e3; \
    unsigned short h0 = f2bf(__expf(s4.x + gumb(UC.x) - my0)); \
    unsigned short h1 = f2bf(__expf(s4.y + gumb(UC.y) - my0)); \
    unsigned short h2 = f2bf(__expf(s4.z + gumb(UC.z) - my0)); \
    unsigned short h3 = f2bf(__expf(s4.w + gumb(UC.w) - my0)); \
    Zy += (bf2f(h0) + bf2f(h1)) + (bf2f(h2) + bf2f(h3)); \
    uint2 pk; pk.x = (unsigned)h0 | ((unsigned)h1 << 16); \
    pk.y = (unsigned)h2 | ((unsigned)h3 << 16); \
    *(uint2*)((char*)Srow + (K) * 512 + 8 * lane) = pk; \
  } while (0)
    PBCHUNK(0, uc0);
    PBCHUNK(1, uc1);
    PBCHUNK(2, uc2);
    PBCHUNK(3, uc3);
#undef PBCHUNK
    // joint reduce (Zs, E1, Zy)
    #pragma unroll
    for (int mk = 1; mk < 64; mk <<= 1) {
      Zs += __shfl_xor(Zs, mk);
      E1 += __shfl_xor(E1, mk);
      Zy += __shfl_xor(Zy, mk);
    }
    float invZ = 1.f / Zs;
    #pragma unroll
    for (int i = 0; i < 16; ++i) pav[i] += et[i] * invZ;
    kd_local += E1 * invZ - __logf(Zs);
    if (lane == 0) zys[lr] = Zy;
  }
  #pragma unroll
  for (int k = 0; k < 4; ++k)
    #pragma unroll
    for (int c = 0; c < 4; ++c)
      atomicAdd(&pavg[k * 256 + 4 * lane + c], pav[4 * k + c]);
  __syncthreads();

  // ---- PD: z_q = E @ codebook (ey bf16 at S rowbase, contiguous 2*c) ----
  st0 = *(const uint4*)(cbtc + t * 32);
  st1 = *(const uint4*)(cbtc + t * 32 + 16);
  f32x4 acc = {0.f, 0.f, 0.f, 0.f};
  const int db = wave >> 1;
  for (int tt = 0; tt < NTILES; ++tt) {
    {
      char* dst = tile + (t >> 3) * 272 + (t & 7) * 32;
      *(uint4*)dst = st0; *(uint4*)(dst + 16) = st1;
    }
    if (tt + 1 < NTILES) {
      st0 = *(const uint4*)(cbtc + (tt + 1) * 16384 + t * 32);
      st1 = *(const uint4*)(cbtc + (tt + 1) * 16384 + t * 32 + 16);
    }
    __syncthreads();
    #pragma unroll
    for (int kb = 0; kb < 4; ++kb) {
      const char* ap = (const char*)S + (rb * 16 + l15) * (SROW * 4) + (tt * 128 + kb * 32 + lg * 8) * 2;
      bf16x8 a = *(const bf16x8*)ap;
      const char* bp = tile + (db * 16 + l15) * 272 + (kb * 32 + lg * 8) * 2;
      bf16x8 b = *(const bf16x8*)bp;
      acc = __builtin_amdgcn_mfma_f32_16x16x32_bf16(a, b, acc, 0, 0, 0);
    }
    __syncthreads();
  }

  // ---- PE: normalize, write out, kld_continuous, flush scalars ----
  float* zq = (float*)tile;
  {
    int col = db * 16 + l15;
    int rl = rb * 16 + lg * 4;
    #pragma unroll
    for (int rr2 = 0; rr2 < 4; ++rr2)
      zq[(rl + rr2) * 64 + col] = acc[rr2] / zys[rl + rr2];
  }
  __syncthreads();
  {
    int row = t >> 4;
    int c4  = (t & 15) << 2;
    *(float4*)(out + (size_t)(r0 + row) * DIM + c4) = *(const float4*)(zq + row * 64 + c4);
  }
  float kc_local = 0.f;
  #pragma unroll
  for (int rr = 0; rr < 4; ++rr) {
    int lr = lr0 + rr;
    float zvv = z[(size_t)(r0 + lr) * DIM + lane];
    float dq = zvv - zq[lr * 64 + lane];
    kc_local += dq * dq;
  }
  kc_local = wsum64(kc_local) * weight;
  if (lane == 0) atomicAdd(lsum, kd_local + kc_local);
  atomicAdd(&avgg[t],       pavg[t]);
  atomicAdd(&avgg[t + 512], pavg[t + 512]);
}

// ---------------- final: loss + perplexity ----------------
__global__ __launch_bounds__(256) void gvq_final(const char* __restrict__ ws, float* __restrict__ out) {
  const float* avgg = (const float*)(ws + WS_AVG);
  const float* lsum = (const float*)(ws + WS_LOSS);
  int t = threadIdx.x;
  float s = 0.f;
  for (int i = t; i < SD; i += 256) {
    float a = avgg[i] * (1.f / 65536.f);
    s += a * logf(a + 1e-7f);
  }
  s = wsum64(s);
  __shared__ float wsums[4];
  if ((t & 63) == 0) wsums[t >> 6] = s;
  __syncthreads();
  if (t == 0) {
    float tot = wsums[0] + wsums[1] + wsums[2] + wsums[3];
    out[(size_t)BS * DIM]     = lsum[0] * (1.f / 65536.f);
    out[(size_t)BS * DIM + 1] = expf(-tot);
  }
}

extern "C" void kernel_launch(void* const* d_in, const int* in_sizes, int n_in,
                              void* d_out, int out_size, void* d_ws, size_t ws_size,
                              hipStream_t stream) {
  (void)in_sizes; (void)n_in; (void)out_size; (void)ws_size;
  const float* z  = (const float*)d_in[0];
  const float* pq = (const float*)d_in[1];
  const float* cb = (const float*)d_in[2];
  const float* u  = (const float*)d_in[3];
  char* ws   = (char*)d_ws;
  float* out = (float*)d_out;
  hipFuncSetAttribute((const void*)gvq_main, hipFuncAttributeMaxDynamicSharedMemorySize, LDS_BYTES);
  gvq_prep<<<4, 256, 0, stream>>>(cb, ws);
  gvq_main<<<BS / TM, NTHREADS, LDS_BYTES, stream>>>(z, pq, u, ws, out);
  gvq_final<<<1, 256, 0, stream>>>(ws, out);
}

// Round 3
// 299.061 us; speedup vs baseline: 1.2711x; 1.1784x over previous
//
#include <hip/hip_runtime.h>

#define BS 65536
#define DIM 64
#define SD 1024
#define TM 32
#define NTHREADS 512
#define NBLK 256
#define NCHUNK 8
#define TILE 128
#define NTILES 8
#define SROW 1028
#define CGS 9.2854e-11f   // exp(-23.1); arbitrary scale, cancels in normalization

// LDS layout (bytes)
#define L_S      0         // [32][1028] f32 scores; PB writes ey bf16 over first 2KB/row
#define L_TILE   131584    // 18432: PA tile 128x144B / PD tile 64x272B / PE zq 32x64 f32
#define L_C2S    150016    // [1024] f32
#define L_Z2S    154112    // [32] f32
#define L_ZYS    154240    // [32] f32
#define L_RMXP   154368    // [4][32] f32 per-cgrp row-max partials
#define L_WRED   154880    // [16] f32
#define LDS_BYTES 155008

// workspace layout (bytes)
#define WS_CBP   0          // 8 tiles x [128 rows x 144B: 64 bf16 + pad]
#define WS_CBT   147456     // 8 tiles x [64 rows(d) x 272B: 128 bf16 + pad]
#define WS_C2    286720     // [1024] f32
#define WS_AVG   290816     // [1024] f32 accumulator (zeroed by prep)
#define WS_APART 294912     // [256][1024] f32 per-block avg partials
#define WS_LPART 1343488    // [256] f32 per-block loss partials

typedef __attribute__((ext_vector_type(8))) short bf16x8;
typedef __attribute__((ext_vector_type(4))) float f32x4;

__device__ __forceinline__ unsigned short f2bf(float f) {
  union { float f; unsigned int u; } v; v.f = f;
  unsigned int r = v.u + 0x7fffu + ((v.u >> 16) & 1u);
  return (unsigned short)(r >> 16);
}
__device__ __forceinline__ float bf2f(unsigned short h) {
  union { unsigned int u; float f; } v; v.u = ((unsigned int)h) << 16;
  return v.f;
}
__device__ __forceinline__ float wsum64(float v) {
  #pragma unroll
  for (int m = 1; m < 64; m <<= 1) v += __shfl_xor(v, m);
  return v;
}
__device__ __forceinline__ bf16x8 pack8(float4 a, float4 b) {
  bf16x8 r;
  r[0]=(short)f2bf(a.x); r[1]=(short)f2bf(a.y); r[2]=(short)f2bf(a.z); r[3]=(short)f2bf(a.w);
  r[4]=(short)f2bf(b.x); r[5]=(short)f2bf(b.y); r[6]=(short)f2bf(b.z); r[7]=(short)f2bf(b.w);
  return r;
}
// barrier with LDS-visibility only: does NOT drain vmcnt -> global prefetch stays in flight
__device__ __forceinline__ void bar() {
  asm volatile("s_waitcnt lgkmcnt(0)" ::: "memory");
  __builtin_amdgcn_s_barrier();
  asm volatile("" ::: "memory");
}

// ---------------- prep: padded bf16 codebook tiles (+transposed), c2, zero avgg ----------------
__global__ __launch_bounds__(256) void gvq_prep(const float* __restrict__ cb, char* __restrict__ ws) {
  int gid = blockIdx.x * 256 + threadIdx.x;   // 0..16383
  int j = gid >> 4, dg = gid & 15;
  float4 v = *(const float4*)(cb + j * DIM + dg * 4);
  float s = v.x*v.x + v.y*v.y + v.z*v.z + v.w*v.w;
  s += __shfl_xor(s, 1); s += __shfl_xor(s, 2); s += __shfl_xor(s, 4); s += __shfl_xor(s, 8);
  int tt = j >> 7, jl = j & 127;
  unsigned short b0 = f2bf(v.x), b1 = f2bf(v.y), b2 = f2bf(v.z), b3 = f2bf(v.w);
  uint2 pk;
  pk.x = (unsigned)b0 | ((unsigned)b1 << 16);
  pk.y = (unsigned)b2 | ((unsigned)b3 << 16);
  *(uint2*)(ws + WS_CBP + tt * 18432 + jl * 144 + dg * 8) = pk;
  unsigned short* tb = (unsigned short*)(ws + WS_CBT + tt * 17408 + jl * 2);
  int d = dg * 4;            // 272B rows = 136 u16 stride
  tb[(d + 0) * 136] = b0; tb[(d + 1) * 136] = b1;
  tb[(d + 2) * 136] = b2; tb[(d + 3) * 136] = b3;
  if (dg == 0) ((float*)(ws + WS_C2))[j] = s;
  if (gid < SD) ((float*)(ws + WS_AVG))[gid] = 0.f;
}

// ---------------- main fused kernel: 256 persistent blocks x 8 chunks ----------------
__global__ __launch_bounds__(NTHREADS, 2) void gvq_main(
    const float* __restrict__ z, const float* __restrict__ pq,
    const float* __restrict__ u, char* __restrict__ ws,
    float* __restrict__ out)
{
  extern __shared__ char smem[];
  float* S    = (float*)(smem + L_S);
  char*  tile = smem + L_TILE;
  float* c2s  = (float*)(smem + L_C2S);
  float* z2s  = (float*)(smem + L_Z2S);
  float* zys  = (float*)(smem + L_ZYS);
  float* rmxp = (float*)(smem + L_RMXP);
  float* wred = (float*)(smem + L_WRED);

  const int t    = threadIdx.x;
  const int lane = t & 63;
  const int wave = t >> 6;
  const int l15  = lane & 15;
  const int lg   = lane >> 4;
  const int rb   = wave & 1;   // 16-row half
  const int cgrp = wave >> 1;  // PA col group / PD d-block
  const int lr0  = wave * 4;   // PB row base

  const char* cbbp = ws + WS_CBP;
  const char* cbtp = ws + WS_CBT;
  const float* c2g = (const float*)(ws + WS_C2);
  float* apart     = (float*)(ws + WS_APART);
  float* lpart     = (float*)(ws + WS_LPART);

  const float weight = 0.5f / fmaxf(pq[0], 1e-10f);

  // once: c2 into LDS
  c2s[t] = c2g[t]; c2s[t + 512] = c2g[t + 512];

  // persistent accumulators
  float pav[16];
  #pragma unroll
  for (int i = 0; i < 16; ++i) pav[i] = 0.f;
  float kd_acc = 0.f, kc_acc = 0.f;

  // prefetch PA tile 0
  uint4 p0, p1, p2;
  p0 = *(const uint4*)(cbbp + t * 16);
  p1 = *(const uint4*)(cbbp + (t + 512) * 16);
  if (t < 128) p2 = *(const uint4*)(cbbp + (t + 1024) * 16);
  float4 ua0, ua1, ua2, ua3;

  for (int c = 0; c < NCHUNK; ++c) {
    const int r0 = (blockIdx.x * NCHUNK + c) * TM;

    // ---- P0: z A-frags direct from global, z2 ----
    const int arow = r0 + rb * 16 + l15;
    float4 za = *(const float4*)(z + (size_t)arow * DIM + lg * 8);
    float4 zb = *(const float4*)(z + (size_t)arow * DIM + lg * 8 + 4);
    float4 zc = *(const float4*)(z + (size_t)arow * DIM + 32 + lg * 8);
    float4 zd = *(const float4*)(z + (size_t)arow * DIM + 32 + lg * 8 + 4);
    bf16x8 a0 = pack8(za, zb);
    bf16x8 a1 = pack8(zc, zd);
    float zsq = za.x*za.x+za.y*za.y+za.z*za.z+za.w*za.w
              + zb.x*zb.x+zb.y*zb.y+zb.z*zb.z+zb.w*zb.w
              + zc.x*zc.x+zc.y*zc.y+zc.z*zc.z+zc.w*zc.w
              + zd.x*zd.x+zd.y*zd.y+zd.z*zd.z+zd.w*zd.w;
    zsq += __shfl_xor(zsq, 16); zsq += __shfl_xor(zsq, 32);
    if (lg == 0) z2s[rb * 16 + l15] = zsq;
    if (c == 0) {
      const float* ur = u + (size_t)(r0 + lr0) * SD + 4 * lane;
      ua0 = *(const float4*)(ur);
      ua1 = *(const float4*)(ur + 256);
      ua2 = *(const float4*)(ur + 512);
      ua3 = *(const float4*)(ur + 768);
    }
    bar();  // chunk start: prior PE tile reads done; z2s visible after next bar anyway

    // ---- PA: S = -w*(z2 + c2 - 2*z.c), per-row max partials ----
    float rmax[4] = {-1e30f, -1e30f, -1e30f, -1e30f};
    for (int tt = 0; tt < NTILES; ++tt) {
      if (tt) bar();
      *(uint4*)(tile + t * 16) = p0;
      *(uint4*)(tile + (t + 512) * 16) = p1;
      if (t < 128) *(uint4*)(tile + (t + 1024) * 16) = p2;
      if (tt + 1 < NTILES) {
        const char* src = cbbp + (tt + 1) * 18432;
        p0 = *(const uint4*)(src + t * 16);
        p1 = *(const uint4*)(src + (t + 512) * 16);
        if (t < 128) p2 = *(const uint4*)(src + (t + 1024) * 16);
      } else {  // prefetch PD tile 0
        p0 = *(const uint4*)(cbtp + t * 16);
        p1 = *(const uint4*)(cbtp + (t + 512) * 16);
        if (t < 64) p2 = *(const uint4*)(cbtp + (t + 1024) * 16);
      }
      bar();
      #pragma unroll
      for (int cbk = 0; cbk < 2; ++cbk) {
        int jl = cgrp * 32 + cbk * 16;
        const char* bp = tile + (jl + l15) * 144 + lg * 16;
        bf16x8 b0 = *(const bf16x8*)bp;
        bf16x8 b1 = *(const bf16x8*)(bp + 64);
        f32x4 acc = {0.f, 0.f, 0.f, 0.f};
        acc = __builtin_amdgcn_mfma_f32_16x16x32_bf16(a0, b0, acc, 0, 0, 0);
        acc = __builtin_amdgcn_mfma_f32_16x16x32_bf16(a1, b1, acc, 0, 0, 0);
        int jg = tt * TILE + jl + l15;
        float c2v = c2s[jg];
        int rl = rb * 16 + lg * 4;
        #pragma unroll
        for (int rr = 0; rr < 4; ++rr) {
          float logit = -weight * (z2s[rl + rr] + c2v - 2.f * acc[rr]);
          S[(rl + rr) * SROW + jg] = logit;
          rmax[rr] = fmaxf(rmax[rr], logit);
        }
      }
    }
    #pragma unroll
    for (int rr = 0; rr < 4; ++rr) {
      float v = rmax[rr];
      v = fmaxf(v, __shfl_xor(v, 1)); v = fmaxf(v, __shfl_xor(v, 2));
      v = fmaxf(v, __shfl_xor(v, 4)); v = fmaxf(v, __shfl_xor(v, 8));
      if (l15 == 0) rmxp[cgrp * 32 + rb * 16 + lg * 4 + rr] = v;
    }
    bar();  // S + rmxp visible (u/tile prefetch stays in flight)

    // ---- PB: e=exp(s-m); ey = e * C/L, L=-log(u+eps)+eps; ey->bf16 in-place ----
    #pragma unroll
    for (int rr = 0; rr < 4; ++rr) {
      const int lr = lr0 + rr;
      float* Srow = S + lr * SROW;
      float4 uc0 = ua0, uc1 = ua1, uc2 = ua2, uc3 = ua3;
      if (rr < 3) {
        const float* un = u + (size_t)(r0 + lr + 1) * SD + 4 * lane;
        ua0 = *(const float4*)(un);
        ua1 = *(const float4*)(un + 256);
        ua2 = *(const float4*)(un + 512);
        ua3 = *(const float4*)(un + 768);
      } else if (c + 1 < NCHUNK) {
        const float* un = u + (size_t)(r0 + TM + lr0) * SD + 4 * lane;
        ua0 = *(const float4*)(un);
        ua1 = *(const float4*)(un + 256);
        ua2 = *(const float4*)(un + 512);
        ua3 = *(const float4*)(un + 768);
      }
      const float m = fmaxf(fmaxf(rmxp[0 * 32 + lr], rmxp[1 * 32 + lr]),
                            fmaxf(rmxp[2 * 32 + lr], rmxp[3 * 32 + lr]));
      float Zs = 0.f, E1 = 0.f, Zy = 0.f;
      float et[16];
#define PBCHUNK(K, UC) do { \
      float4 s4 = *(const float4*)(Srow + (K) * 256 + 4 * lane); \
      float d0 = s4.x - m, d1 = s4.y - m, d2 = s4.z - m, d3 = s4.w - m; \
      float e0 = __expf(d0), e1 = __expf(d1), e2 = __expf(d2), e3 = __expf(d3); \
      Zs += (e0 + e1) + (e2 + e3); \
      E1 += (e0 * d0 + e1 * d1) + (e2 * d2 + e3 * d3); \
      et[(K)*4+0] = e0; et[(K)*4+1] = e1; et[(K)*4+2] = e2; et[(K)*4+3] = e3; \
      float L0 = 1e-10f - __logf(UC.x + 1e-10f); \
      float L1 = 1e-10f - __logf(UC.y + 1e-10f); \
      float L2 = 1e-10f - __logf(UC.z + 1e-10f); \
      float L3 = 1e-10f - __logf(UC.w + 1e-10f); \
      unsigned short h0 = f2bf(e0 * (CGS * __builtin_amdgcn_rcpf(L0))); \
      unsigned short h1 = f2bf(e1 * (CGS * __builtin_amdgcn_rcpf(L1))); \
      unsigned short h2 = f2bf(e2 * (CGS * __builtin_amdgcn_rcpf(L2))); \
      unsigned short h3 = f2bf(e3 * (CGS * __builtin_amdgcn_rcpf(L3))); \
      Zy += (bf2f(h0) + bf2f(h1)) + (bf2f(h2) + bf2f(h3)); \
      uint2 pk; pk.x = (unsigned)h0 | ((unsigned)h1 << 16); \
      pk.y = (unsigned)h2 | ((unsigned)h3 << 16); \
      *(uint2*)((char*)Srow + (K) * 512 + 8 * lane) = pk; \
    } while (0)
      PBCHUNK(0, uc0);
      PBCHUNK(1, uc1);
      PBCHUNK(2, uc2);
      PBCHUNK(3, uc3);
#undef PBCHUNK
      #pragma unroll
      for (int mk = 1; mk < 64; mk <<= 1) {
        Zs += __shfl_xor(Zs, mk);
        E1 += __shfl_xor(E1, mk);
        Zy += __shfl_xor(Zy, mk);
      }
      float invZ = 1.f / Zs;
      #pragma unroll
      for (int i = 0; i < 16; ++i) pav[i] += et[i] * invZ;
      kd_acc += E1 * invZ - __logf(Zs);
      if (lane == 0) zys[lr] = Zy;
    }
    bar();  // ey + zys visible

    // ---- PD: z_q raw = Ey @ codebook ----
    f32x4 dacc = {0.f, 0.f, 0.f, 0.f};
    for (int tt = 0; tt < NTILES; ++tt) {
      if (tt) bar();
      *(uint4*)(tile + t * 16) = p0;
      *(uint4*)(tile + (t + 512) * 16) = p1;
      if (t < 64) *(uint4*)(tile + (t + 1024) * 16) = p2;
      if (tt + 1 < NTILES) {
        const char* src = cbtp + (tt + 1) * 17408;
        p0 = *(const uint4*)(src + t * 16);
        p1 = *(const uint4*)(src + (t + 512) * 16);
        if (t < 64) p2 = *(const uint4*)(src + (t + 1024) * 16);
      } else if (c + 1 < NCHUNK) {  // prefetch next chunk PA tile 0
        p0 = *(const uint4*)(cbbp + t * 16);
        p1 = *(const uint4*)(cbbp + (t + 512) * 16);
        if (t < 128) p2 = *(const uint4*)(cbbp + (t + 1024) * 16);
      }
      bar();
      #pragma unroll
      for (int kb = 0; kb < 4; ++kb) {
        const char* ap = (const char*)S + (rb * 16 + l15) * (SROW * 4) + (tt * 128 + kb * 32 + lg * 8) * 2;
        bf16x8 a = *(const bf16x8*)ap;
        const char* bp = tile + (cgrp * 16 + l15) * 272 + (kb * 32 + lg * 8) * 2;
        bf16x8 b = *(const bf16x8*)bp;
        dacc = __builtin_amdgcn_mfma_f32_16x16x32_bf16(a, b, dacc, 0, 0, 0);
      }
    }
    bar();  // tile reads done before zq overwrite

    // ---- PE: normalize into zq (tile region), write out, kc ----
    float* zq = (float*)tile;
    {
      int col = cgrp * 16 + l15;
      int rl = rb * 16 + lg * 4;
      #pragma unroll
      for (int rr = 0; rr < 4; ++rr)
        zq[(rl + rr) * 64 + col] = dacc[rr] / zys[rl + rr];
    }
    bar();
    {
      int row = t >> 4;
      int c4  = (t & 15) << 2;
      *(float4*)(out + (size_t)(r0 + row) * DIM + c4) = *(const float4*)(zq + row * 64 + c4);
    }
    float kcl = 0.f;
    #pragma unroll
    for (int rr = 0; rr < 4; ++rr) {
      int lr = lr0 + rr;
      float zvv = z[(size_t)(r0 + lr) * DIM + lane];
      float dq = zvv - zq[lr * 64 + lane];
      kcl += dq * dq;
    }
    kc_acc += wsum64(kcl) * weight;
  }

  // ---- flush: per-block partials (no global atomics) ----
  bar();
  float* pavb = (float*)smem;  // reuse S region: [8][1024] f32
  #pragma unroll
  for (int k = 0; k < 4; ++k) {
    float4 v4 = {pav[4*k+0], pav[4*k+1], pav[4*k+2], pav[4*k+3]};
    *(float4*)(pavb + wave * 1024 + k * 256 + 4 * lane) = v4;
  }
  if (lane == 0) wred[wave] = kd_acc + kc_acc;
  bar();
  {
    int c0 = t, c1 = t + 512;
    float s0 = 0.f, s1 = 0.f;
    #pragma unroll
    for (int w = 0; w < 8; ++w) { s0 += pavb[w * 1024 + c0]; s1 += pavb[w * 1024 + c1]; }
    apart[(size_t)blockIdx.x * 1024 + c0] = s0;
    apart[(size_t)blockIdx.x * 1024 + c1] = s1;
    if (t == 0) {
      float L = 0.f;
      #pragma unroll
      for (int w = 0; w < 8; ++w) L += wred[w];
      lpart[blockIdx.x] = L;
    }
  }
}

// ---------------- reduce avg partials: 32 blocks x 8 rows each ----------------
__global__ __launch_bounds__(512) void gvq_red(char* __restrict__ ws) {
  const float* apart = (const float*)(ws + WS_APART);
  float* avgg        = (float*)(ws + WS_AVG);
  int bb = blockIdx.x, t = threadIdx.x;
  float s0 = 0.f, s1 = 0.f;
  #pragma unroll
  for (int r = 0; r < 8; ++r) {
    float2 v = *(const float2*)(apart + (size_t)(bb * 8 + r) * 1024 + t * 2);
    s0 += v.x; s1 += v.y;
  }
  atomicAdd(&avgg[t * 2], s0);
  atomicAdd(&avgg[t * 2 + 1], s1);
}

// ---------------- final: loss + perplexity ----------------
__global__ __launch_bounds__(256) void gvq_final(const char* __restrict__ ws, float* __restrict__ out) {
  const float* avgg  = (const float*)(ws + WS_AVG);
  const float* lpart = (const float*)(ws + WS_LPART);
  int t = threadIdx.x;
  float s = 0.f;
  #pragma unroll
  for (int i = t; i < SD; i += 256) {
    float a = avgg[i] * (1.f / 65536.f);
    s += a * logf(a + 1e-7f);
  }
  float lp = lpart[t];
  s = wsum64(s); lp = wsum64(lp);
  __shared__ float ws1[4], ws2[4];
  if ((t & 63) == 0) { ws1[t >> 6] = s; ws2[t >> 6] = lp; }
  __syncthreads();
  if (t == 0) {
    float tot = ws1[0] + ws1[1] + ws1[2] + ws1[3];
    float L   = ws2[0] + ws2[1] + ws2[2] + ws2[3];
    out[(size_t)BS * DIM]     = L * (1.f / 65536.f);
    out[(size_t)BS * DIM + 1] = expf(-tot);
  }
}

extern "C" void kernel_launch(void* const* d_in, const int* in_sizes, int n_in,
                              void* d_out, int out_size, void* d_ws, size_t ws_size,
                              hipStream_t stream) {
  (void)in_sizes; (void)n_in; (void)out_size; (void)ws_size;
  const float* z  = (const float*)d_in[0];
  const float* pq = (const float*)d_in[1];
  const float* cb = (const float*)d_in[2];
  const float* u  = (const float*)d_in[3];
  char* ws   = (char*)d_ws;
  float* out = (float*)d_out;
  hipFuncSetAttribute((const void*)gvq_main, hipFuncAttributeMaxDynamicSharedMemorySize, LDS_BYTES);
  gvq_prep<<<64, 256, 0, stream>>>(cb, ws);
  gvq_main<<<NBLK, NTHREADS, LDS_BYTES, stream>>>(z, pq, u, ws, out);
  gvq_red<<<32, 512, 0, stream>>>(ws);
  gvq_final<<<1, 256, 0, stream>>>(ws, out);
}